// Round 23
// baseline (272.584 us; speedup 1.0000x reference)
//
#include <hip/hip_runtime.h>
#include <math.h>

// B=4, N=2048, H=8, CM=8, CS=16 ; head dim 144 padded to 160 (5 chunks of 32)
// qf/kf/vf: bf16 (b,h,n,160); ho: bf16 (b,h,n,144) head-contiguous
// Softmax in exp2 domain (QSCALE = (1/12)*log2(e) folded into q).
// V[d=144] = 1.0 so PV's dblk-9 accumulates the softmax denominator l.

typedef float f32x4 __attribute__((ext_vector_type(4)));
typedef __bf16 bf16x8 __attribute__((ext_vector_type(8)));
typedef unsigned short u16;
typedef unsigned int u32;

#define QSCALE 0.120224586740747f   // (1/12) * log2(e)
#define DEFER_THR 11.541560f        // 8 * log2(e)

__device__ __forceinline__ u32 pack2(float a, float b) {
  u32 ua = __builtin_bit_cast(u32, a);
  u32 ub = __builtin_bit_cast(u32, b);
  ua = (ua + 0x7fffu + ((ua >> 16) & 1u)) >> 16;
  ub = (ub + 0x7fffu + ((ub >> 16) & 1u)) >> 16;
  return ua | (ub << 16);
}
__device__ __forceinline__ u16 bf16of(float a) { return (u16)(pack2(a, 0.f) & 0xffffu); }

__device__ __forceinline__ u32 cvtpk(float lo, float hi) {
  u32 r;
  asm("v_cvt_pk_bf16_f32 %0, %1, %2" : "=v"(r) : "v"(lo), "v"(hi));
  return r;
}
__device__ __forceinline__ float lo16f(u32 w) { return __builtin_bit_cast(float, w << 16); }
__device__ __forceinline__ float hi16f(u32 w) { return __builtin_bit_cast(float, w & 0xffff0000u); }

__device__ __forceinline__ f32x4 mfma_bf16(uint4 a, uint4 b, f32x4 c) {
  return __builtin_amdgcn_mfma_f32_16x16x32_bf16(
      __builtin_bit_cast(bf16x8, a), __builtin_bit_cast(bf16x8, b), c, 0, 0, 0);
}

__device__ __forceinline__ uint2 tr16(u32 addr) {
  uint2 r;
  asm volatile("ds_read_b64_tr_b16 %0, %1" : "=v"(r) : "v"(addr));
  return r;
}

__device__ __forceinline__ void glds16(const void* g, void* l) {
  __builtin_amdgcn_global_load_lds((const __attribute__((address_space(1))) void*)g,
                                   (__attribute__((address_space(3))) void*)l, 16, 0, 0);
}

// ---------------------------------------------------------------------------
// Q projection (R20). 256 threads, 8 tokens/block. Direct global token reads
// (wave-uniform -> scalarized). Output staged in qs for coalesced stores.
// ---------------------------------------------------------------------------
__global__ __launch_bounds__(256) void k_proj_q(
    const float* __restrict__ mv, const float* __restrict__ sc,
    const float* __restrict__ w_mv, const float* __restrict__ w_s2mv,
    const float* __restrict__ w_mv2s, const float* __restrict__ w_s,
    u16* __restrict__ qf)
{
  __shared__ u16 qs[8*8*168];
  const int t = threadIdx.x;
  const int tok0 = blockIdx.x * 8;
  const int b0 = tok0 >> 11, n0 = tok0 & 2047;

  if (t < 128) {
    const int o = t & 63, h2 = t >> 6;
    float wreg[3][16];
    #pragma unroll
    for (int j = 0; j < 3; ++j)
      #pragma unroll
      for (int i = 0; i < 16; ++i)
        wreg[j][i] = w_mv[(((h2*2 + j)*64) + o)*16 + i];
    float ws2[32];
    if (h2 == 0)
      #pragma unroll
      for (int j = 0; j < 32; ++j) ws2[j] = w_s2mv[o*32 + j];
    const int c = o >> 3, hh = o & 7;
    for (int tk = 0; tk < 8; ++tk) {
      const float* L  = &mv[(size_t)(tok0+tk)*256];
      const float* Ls = &sc[(size_t)(tok0+tk)*32];
      float acc[8] = {0,0,0,0,0,0,0,0};
      if (h2 == 0) {
        #pragma unroll
        for (int i = 0; i < 16; ++i) {
          const float w0 = wreg[0][i], w1 = wreg[1][i], w2 = wreg[2][i];
          const float4 A = *(const float4*)&L[i*16];
          const float4 Bv = *(const float4*)&L[i*16 + 4];
          acc[0] += A.x*w0;  acc[1] += A.y*w1;  acc[2] += A.z*w1;  acc[3] += A.w*w1;
          acc[4] += Bv.x*w1; acc[5] += Bv.y*w2; acc[6] += Bv.z*w2; acc[7] += Bv.w*w2;
        }
        float a0 = 0.f;
        #pragma unroll
        for (int j4 = 0; j4 < 8; ++j4) {
          const float4 s4 = *(const float4*)&Ls[j4*4];
          a0 += s4.x*ws2[j4*4] + s4.y*ws2[j4*4+1] + s4.z*ws2[j4*4+2] + s4.w*ws2[j4*4+3];
        }
        acc[0] += a0;
        acc[0] *= QSCALE; acc[1] *= QSCALE;
        #pragma unroll
        for (int xx = 2; xx < 8; ++xx) acc[xx] *= -QSCALE;
      } else {
        #pragma unroll
        for (int i = 0; i < 16; ++i) {
          const float w0 = wreg[0][i], w1 = wreg[1][i], w2 = wreg[2][i];
          const float4 A = *(const float4*)&L[i*16 + 8];
          const float4 Bv = *(const float4*)&L[i*16 + 12];
          acc[0] += A.x*w0;  acc[1] += A.y*w0;  acc[2] += A.z*w0;  acc[3] += A.w*w1;
          acc[4] += Bv.x*w1; acc[5] += Bv.y*w1; acc[6] += Bv.z*w1; acc[7] += Bv.w*w2;
        }
        #pragma unroll
        for (int xx = 0; xx < 6; ++xx) acc[xx] *= QSCALE;
        acc[6] *= -QSCALE; acc[7] *= -QSCALE;
      }
      uint4 u; u.x = pack2(acc[0],acc[1]); u.y = pack2(acc[2],acc[3]);
      u.z = pack2(acc[4],acc[5]); u.w = pack2(acc[6],acc[7]);
      *(uint4*)&qs[(tk*8 + hh)*168 + c*16 + h2*8] = u;
    }
  } else {
    const int o2 = t - 128;
    float wsv[32], wm2[16];
    #pragma unroll
    for (int j = 0; j < 32; ++j) wsv[j] = w_s[o2*32 + j];
    #pragma unroll
    for (int i = 0; i < 16; ++i) wm2[i] = w_mv2s[o2*16 + i];
    const int cs = o2 >> 3, hh = o2 & 7;
    for (int tk = 0; tk < 8; ++tk) {
      const float* L  = &mv[(size_t)(tok0+tk)*256];
      const float* Ls = &sc[(size_t)(tok0+tk)*32];
      float a = 0.f;
      #pragma unroll
      for (int j4 = 0; j4 < 8; ++j4) {
        const float4 s4 = *(const float4*)&Ls[j4*4];
        a += s4.x*wsv[j4*4] + s4.y*wsv[j4*4+1] + s4.z*wsv[j4*4+2] + s4.w*wsv[j4*4+3];
      }
      #pragma unroll
      for (int i = 0; i < 16; ++i) a += L[i*16]*wm2[i];
      qs[(tk*8 + hh)*168 + 128 + cs] = bf16of(a * QSCALE);
    }
  }
  __syncthreads();
  for (int idx = t; idx < 8*8*20; idx += 256) {
    const int hh = idx / 160, rem = idx - hh*160;
    const int tk = rem / 20, u = rem - tk*20;
    uint4 v = (u < 18) ? *(const uint4*)&qs[(tk*8 + hh)*168 + u*8] : uint4{0,0,0,0};
    *(uint4*)(qf + ((size_t)(b0*8 + hh)*2048 + n0 + tk)*160 + u*8) = v;
  }
}

// ---------------------------------------------------------------------------
// KV projection (R20). 512 threads, 8 tokens/block, direct global reads.
// V pad gets bf16(1.0) at d=144.
// ---------------------------------------------------------------------------
__global__ __launch_bounds__(512) void k_proj_kv(
    const float* __restrict__ mv, const float* __restrict__ sc,
    const float* __restrict__ w_mv, const float* __restrict__ w_s2mv,
    const float* __restrict__ w_mv2s, const float* __restrict__ w_s,
    u16* __restrict__ kf, u16* __restrict__ vf)
{
  __shared__ u16 kvs[2*8*8*168];   // [isv][tk][hh][168]
  const int t = threadIdx.x;
  const int tok0 = blockIdx.x * 8;
  const int b0 = tok0 >> 11, n0 = tok0 & 2047;

  if (t < 256) {
    const int o = t & 127, h2 = t >> 7;
    float wreg[3][16];
    #pragma unroll
    for (int j = 0; j < 3; ++j)
      #pragma unroll
      for (int i = 0; i < 16; ++i)
        wreg[j][i] = w_mv[(((h2*2 + j)*128) + o)*16 + i];
    float ws2[32];
    if (h2 == 0)
      #pragma unroll
      for (int j = 0; j < 32; ++j) ws2[j] = w_s2mv[o*32 + j];
    const int isv = o >> 6, oo = o & 63;
    const int c = oo >> 3, hh = oo & 7;
    u16* stg = &kvs[isv*8*8*168];
    for (int tk = 0; tk < 8; ++tk) {
      const float* L  = &mv[(size_t)(tok0+tk)*256];
      const float* Ls = &sc[(size_t)(tok0+tk)*32];
      float acc[8] = {0,0,0,0,0,0,0,0};
      if (h2 == 0) {
        #pragma unroll
        for (int i = 0; i < 16; ++i) {
          const float w0 = wreg[0][i], w1 = wreg[1][i], w2 = wreg[2][i];
          const float4 A = *(const float4*)&L[i*16];
          const float4 Bv = *(const float4*)&L[i*16 + 4];
          acc[0] += A.x*w0;  acc[1] += A.y*w1;  acc[2] += A.z*w1;  acc[3] += A.w*w1;
          acc[4] += Bv.x*w1; acc[5] += Bv.y*w2; acc[6] += Bv.z*w2; acc[7] += Bv.w*w2;
        }
        float a0 = 0.f;
        #pragma unroll
        for (int j4 = 0; j4 < 8; ++j4) {
          const float4 s4 = *(const float4*)&Ls[j4*4];
          a0 += s4.x*ws2[j4*4] + s4.y*ws2[j4*4+1] + s4.z*ws2[j4*4+2] + s4.w*ws2[j4*4+3];
        }
        acc[0] += a0;
      } else {
        #pragma unroll
        for (int i = 0; i < 16; ++i) {
          const float w0 = wreg[0][i], w1 = wreg[1][i], w2 = wreg[2][i];
          const float4 A = *(const float4*)&L[i*16 + 8];
          const float4 Bv = *(const float4*)&L[i*16 + 12];
          acc[0] += A.x*w0;  acc[1] += A.y*w0;  acc[2] += A.z*w0;  acc[3] += A.w*w1;
          acc[4] += Bv.x*w1; acc[5] += Bv.y*w1; acc[6] += Bv.z*w1; acc[7] += Bv.w*w2;
        }
      }
      uint4 u; u.x = pack2(acc[0],acc[1]); u.y = pack2(acc[2],acc[3]);
      u.z = pack2(acc[4],acc[5]); u.w = pack2(acc[6],acc[7]);
      *(uint4*)&stg[(tk*8 + hh)*168 + c*16 + h2*8] = u;
    }
  } else {
    const int o2 = t - 256;
    float wsv[32], wm2[16];
    #pragma unroll
    for (int j = 0; j < 32; ++j) wsv[j] = w_s[o2*32 + j];
    #pragma unroll
    for (int i = 0; i < 16; ++i) wm2[i] = w_mv2s[o2*16 + i];
    const int isv = o2 >> 7, oo2 = o2 & 127;
    const int cs = oo2 >> 3, hh = oo2 & 7;
    u16* stg = &kvs[isv*8*8*168];
    for (int tk = 0; tk < 8; ++tk) {
      const float* L  = &mv[(size_t)(tok0+tk)*256];
      const float* Ls = &sc[(size_t)(tok0+tk)*32];
      float a = 0.f;
      #pragma unroll
      for (int j4 = 0; j4 < 8; ++j4) {
        const float4 s4 = *(const float4*)&Ls[j4*4];
        a += s4.x*wsv[j4*4] + s4.y*wsv[j4*4+1] + s4.z*wsv[j4*4+2] + s4.w*wsv[j4*4+3];
      }
      #pragma unroll
      for (int i = 0; i < 16; ++i) a += L[i*16]*wm2[i];
      stg[(tk*8 + hh)*168 + 128 + cs] = bf16of(a);
    }
  }
  __syncthreads();
  for (int idx = t; idx < 2560; idx += 512) {
    const int isv = idx / 1280;
    const int r = idx - isv*1280;
    const int hh = r / 160, rem = r - hh*160;
    const int tk = rem / 20, u = rem - tk*20;
    uint4 v;
    if (u < 18)               v = *(const uint4*)&kvs[isv*8*8*168 + (tk*8 + hh)*168 + u*8];
    else if (u == 18 && isv)  v = uint4{0x3F80u, 0, 0, 0};   // V[d=144] = 1.0
    else                      v = uint4{0, 0, 0, 0};
    u16* base = isv ? vf : kf;
    *(uint4*)(base + ((size_t)(b0*8 + hh)*2048 + n0 + tk)*160 + u*8) = v;
  }
}

// ---------------------------------------------------------------------------
// Flash attention: KVBLK=64, K read DIRECTLY from global (L2-resident panel,
// coalesced per-(ks,dc) instruction) -- no K staging, no K LDS reads.
// V double-buffered in LDS for tr16 transpose. l-in-MFMA, bf16 ho.
// LDS: 2 x 20480 = 40960 B.
// ---------------------------------------------------------------------------
__global__ __launch_bounds__(256, 2) void k_attn(
    const u16* __restrict__ qf, const u16* __restrict__ kf,
    const u16* __restrict__ vf, const float* __restrict__ hsc,
    u16* __restrict__ ho)
{
  __shared__ __align__(16) char smem[40960];

  const int orig = blockIdx.x;
  const int bid = (orig & 7) * 64 + (orig >> 3);   // XCD-contiguous (512%8==0)
  const int qt = bid & 15;
  const int bh = bid >> 4;
  const int h  = bh & 7;
  const int t  = threadIdx.x;
  const int w  = t >> 6;
  const int lane = t & 63;
  const int qi = lane & 15;
  const int hi = lane >> 4;

  const u16* kg  = kf + (size_t)bh * 2048 * 160;
  const char* vgB = (const char*)(vf + (size_t)bh * 2048 * 160);
  const u16* qg = qf + ((size_t)bh * 2048 + qt*128 + w*32) * 160;
  const float hsv = hsc[h];

  uint4 qfr0[5], qfr1[5];
  #pragma unroll
  for (int dc = 0; dc < 5; ++dc) {
    qfr0[dc] = *(const uint4*)(qg + (size_t)qi*160 + dc*32 + hi*8);
    qfr1[dc] = *(const uint4*)(qg + (size_t)(16 + qi)*160 + dc*32 + hi*8);
  }

  f32x4 o0[10], o1[10];
  #pragma unroll
  for (int d = 0; d < 10; ++d) { o0[d] = f32x4{0,0,0,0}; o1[d] = f32x4{0,0,0,0}; }
  float m0 = -INFINITY, m1 = -INFINITY;

  // V staging: wave w stages kblk w (5120 B = [10 dblk][16 krow][16 bf16]).
  // dest linear = buf*20480 + w*5120 + j*1024 (+ lane*16 implicit);
  // src (row, col): r1 = j*1024 + lane*16; dblk=r1>>9, krow=(r1>>5)&15,
  // dhalf=(r1>>4)&1; soff = (w*16+krow)*320 + dblk*32 + dhalf*16 bytes.
  int soff[5];
  #pragma unroll
  for (int j = 0; j < 5; ++j) {
    const int r1 = j*1024 + lane*16;
    const int dblk = r1 >> 9, krow = (r1 >> 5) & 15, dhalf = (r1 >> 4) & 1;
    soff[j] = (w*16 + krow)*320 + dblk*32 + dhalf*16;
  }

  #define STAGE(KT, BUF) do {                                              \
    char* vb_ = smem + (BUF)*20480 + w*5120;                               \
    const char* src_ = vgB + (size_t)(KT)*20480;                           \
    _Pragma("unroll")                                                      \
    for (int j = 0; j < 5; ++j)                                            \
      glds16(src_ + soff[j], vb_ + j*1024);                                \
  } while (0)

  STAGE(0, 0);
  __syncthreads();

  for (int kt = 0; kt < 32; ++kt) {
    const int buf = kt & 1;
    if (kt < 31) STAGE(kt+1, buf^1);

    const u32 VoffB = (u32)(buf*20480);

    // ---- S^T = K * Q^T : K A-frags straight from global (L2-hit) ----
    f32x4 st0[4], st1[4];
    __builtin_amdgcn_s_setprio(1);
    #pragma unroll
    for (int ks = 0; ks < 4; ++ks) {
      st0[ks] = f32x4{0,0,0,0};
      st1[ks] = f32x4{0,0,0,0};
      const u16* krow = kg + (size_t)(kt*64 + ks*16 + qi)*160 + hi*8;
      #pragma unroll
      for (int dc = 0; dc < 5; ++dc) {
        const uint4 kf4 = *(const uint4*)(krow + dc*32);
        st0[ks] = mfma_bf16(kf4, qfr0[dc], st0[ks]);
        st1[ks] = mfma_bf16(kf4, qfr1[dc], st1[ks]);
      }
    }
    __builtin_amdgcn_s_setprio(0);

    float pm0 = st0[0][0], pm1 = st1[0][0];
    #pragma unroll
    for (int ks = 0; ks < 4; ++ks)
      #pragma unroll
      for (int r = 0; r < 4; ++r) {
        pm0 = fmaxf(pm0, st0[ks][r]);
        pm1 = fmaxf(pm1, st1[ks][r]);
      }
    pm0 = fmaxf(pm0, __shfl_xor(pm0, 16)); pm0 = fmaxf(pm0, __shfl_xor(pm0, 32));
    pm1 = fmaxf(pm1, __shfl_xor(pm1, 16)); pm1 = fmaxf(pm1, __shfl_xor(pm1, 32));
    if (!__all(fmaxf(pm0 - m0, pm1 - m1) <= DEFER_THR)) {
      const float mn0 = fmaxf(m0, pm0), mn1 = fmaxf(m1, pm1);
      const float rs0 = exp2f(m0 - mn0), rs1 = exp2f(m1 - mn1);
      m0 = mn0; m1 = mn1;
      float rr0[4], rr1[4];
      #pragma unroll
      for (int r = 0; r < 4; ++r) {
        rr0[r] = __shfl(rs0, hi*4 + r);
        rr1[r] = __shfl(rs1, hi*4 + r);
      }
      #pragma unroll
      for (int d = 0; d < 10; ++d)
        #pragma unroll
        for (int r = 0; r < 4; ++r) { o0[d][r] *= rr0[r]; o1[d][r] *= rr1[r]; }
    }
    #pragma unroll
    for (int ks = 0; ks < 4; ++ks)
      #pragma unroll
      for (int r = 0; r < 4; ++r) {
        st0[ks][r] = exp2f(st0[ks][r] - m0);
        st1[ks][r] = exp2f(st1[ks][r] - m1);
      }

    uint4 pb0a, pb0b, pb1a, pb1b;
    pb0a.x = cvtpk(st0[0][0], st0[0][1]); pb0a.y = cvtpk(st0[0][2], st0[0][3]);
    pb0a.z = cvtpk(st0[1][0], st0[1][1]); pb0a.w = cvtpk(st0[1][2], st0[1][3]);
    pb0b.x = cvtpk(st0[2][0], st0[2][1]); pb0b.y = cvtpk(st0[2][2], st0[2][3]);
    pb0b.z = cvtpk(st0[3][0], st0[3][1]); pb0b.w = cvtpk(st0[3][2], st0[3][3]);
    pb1a.x = cvtpk(st1[0][0], st1[0][1]); pb1a.y = cvtpk(st1[0][2], st1[0][3]);
    pb1a.z = cvtpk(st1[1][0], st1[1][1]); pb1a.w = cvtpk(st1[1][2], st1[1][3]);
    pb1b.x = cvtpk(st1[2][0], st1[2][1]); pb1b.y = cvtpk(st1[2][2], st1[2][3]);
    pb1b.z = cvtpk(st1[3][0], st1[3][1]); pb1b.w = cvtpk(st1[3][2], st1[3][3]);

    // ---- O += P * V : V layout [kblk 4][dblk 10][16][16] per buffer ----
    const u32 vtb = VoffB + (u32)(hi*128 + (qi>>2)*32 + (qi&3)*8);
    __builtin_amdgcn_s_setprio(1);
    #pragma unroll
    for (int ds = 0; ds < 10; ++ds) {
      const u32 a0 = vtb + ds*512;
      uint2 t0 = tr16(a0);
      uint2 t1 = tr16(a0 + 5120);
      uint2 t2 = tr16(a0 + 10240);
      uint2 t3 = tr16(a0 + 15360);
      asm volatile("s_waitcnt lgkmcnt(0)" ::: "memory");
      __builtin_amdgcn_sched_barrier(0);
      const uint4 vb01{t0.x, t0.y, t1.x, t1.y};
      const uint4 vb23{t2.x, t2.y, t3.x, t3.y};
      o0[ds] = mfma_bf16(pb0a, vb01, o0[ds]);
      o0[ds] = mfma_bf16(pb0b, vb23, o0[ds]);
      o1[ds] = mfma_bf16(pb1a, vb01, o1[ds]);
      o1[ds] = mfma_bf16(pb1b, vb23, o1[ds]);
    }
    __builtin_amdgcn_s_setprio(0);

    __syncthreads();   // drains vmcnt(0): next V tile staged; prev reads done
  }

  // ---- epilogue: bf16 ho stores ----
  float ir0[4], ir1[4];
  #pragma unroll
  for (int r = 0; r < 4; ++r) {
    ir0[r] = hsv / __shfl(o0[9][r], hi*16);
    ir1[r] = hsv / __shfl(o1[9][r], hi*16);
  }
  float (*Ol)[148] = reinterpret_cast<float(*)[148]>(smem);  // 37888 B <= 40960
  const size_t obase = ((size_t)bh*2048 + qt*128) * 144;
  #pragma unroll
  for (int f = 0; f < 2; ++f) {
    #pragma unroll
    for (int ds = 0; ds < 9; ++ds)
      #pragma unroll
      for (int r = 0; r < 4; ++r) {
        const int q = w*16 + hi*4 + r;
        const int loc = (ds < 8) ? (qi*8 + ds) : (128 + qi);
        Ol[q][loc] = (f ? o1[ds][r]*ir1[r] : o0[ds][r]*ir0[r]);
      }
    __syncthreads();
    for (int idx = t; idx < 64*18; idx += 256) {
      const int q = idx / 18, u = idx - q*18;
      const int grow = (q >> 4)*32 + f*16 + (q & 15);
      const float4 a = *(const float4*)&Ol[q][u*8];
      const float4 b = *(const float4*)&Ol[q][u*8 + 4];
      uint4 pk;
      pk.x = cvtpk(a.x, a.y); pk.y = cvtpk(a.z, a.w);
      pk.z = cvtpk(b.x, b.y); pk.w = cvtpk(b.z, b.w);
      *(uint4*)(ho + obase + (size_t)grow*144 + u*8) = pk;
    }
    __syncthreads();
  }
  #undef STAGE
}

// ---------------------------------------------------------------------------
// Output projection (R18/R20). 256 threads, 8 tokens/block, bf16 ho input.
// Gather-fill into LDS (coalesced), compute from LDS.
// ---------------------------------------------------------------------------
__global__ __launch_bounds__(256) void k_out(
    const u16* __restrict__ ho,
    const float* __restrict__ w_mv, const float* __restrict__ w_s2mv,
    const float* __restrict__ w_mv2s, const float* __restrict__ w_s,
    float* __restrict__ out)
{
  constexpr int kGx[16] = {0,1,1,1,1,2,2,2,2,2,2,3,3,3,3,4};
  __shared__ float lh[8*1152];
  __shared__ float ob[256];
  __shared__ float csl[16];
  const int t = threadIdx.x;
  const int tok0 = blockIdx.x * 8;
  const int b0 = tok0 >> 11, n0 = tok0 & 2047;

  const int x = t >> 4, oB = t & 15;
  float4 wB[16];
  #pragma unroll
  for (int q = 0; q < 16; ++q)
    wB[q] = *(const float4*)&w_mv[(kGx[x]*16 + oB)*64 + q*4];

  float wC[16];
  float wD1[32], wD2[16];
  int oC = 0, pC = 0, oD = 0, pD = 0;
  if (t < 128) {
    oC = t >> 3; pC = t & 7;
    #pragma unroll
    for (int j = 0; j < 16; ++j) wC[j] = w_s2mv[oC*128 + pC*16 + j];
  } else {
    const int tt = t - 128;
    oD = tt >> 2; pD = tt & 3;
    #pragma unroll
    for (int j = 0; j < 32; ++j) wD1[j] = w_s[oD*128 + pD*32 + j];
    #pragma unroll
    for (int j = 0; j < 16; ++j) wD2[j] = w_mv2s[oD*64 + pD*16 + j];
  }

  // gather-fill: 8 tk x 8 heads x 18 uint4 (8 bf16 each)
  for (int idx = t; idx < 1152; idx += 256) {
    const int tk = idx / 144, rem = idx - tk*144;
    const int hh = rem / 18, u8 = rem - hh*18;
    const uint4 v = *(const uint4*)&ho[(((size_t)(b0*8 + hh)*2048) + n0 + tk)*144 + u8*8];
    float* Lt = &lh[tk*1152];
    const int dst = (u8 < 16) ? (u8*64 + hh*8) : (1024 + hh*16 + (u8-16)*8);
    *(float4*)&Lt[dst]     = float4{lo16f(v.x), hi16f(v.x), lo16f(v.y), hi16f(v.y)};
    *(float4*)&Lt[dst + 4] = float4{lo16f(v.z), hi16f(v.z), lo16f(v.w), hi16f(v.w)};
  }
  __syncthreads();

  for (int tk = 0; tk < 8; ++tk) {
    const float* hp = &lh[tk*1152];
    float acc = 0.f;
    #pragma unroll
    for (int q = 0; q < 16; ++q) {
      const float4 hv = *(const float4*)&hp[x*64 + q*4];
      acc += hv.x*wB[q].x + hv.y*wB[q].y + hv.z*wB[q].z + hv.w*wB[q].w;
    }
    ob[t] = acc;
    if (t < 128) {
      float a = 0.f;
      #pragma unroll
      for (int j = 0; j < 16; ++j) a += hp[1024 + pC*16 + j]*wC[j];
      a += __shfl_xor(a, 1); a += __shfl_xor(a, 2); a += __shfl_xor(a, 4);
      if (pC == 0) csl[oC] = a;
    } else {
      float a = 0.f;
      #pragma unroll
      for (int j = 0; j < 32; ++j) a += hp[1024 + pD*32 + j]*wD1[j];
      #pragma unroll
      for (int j = 0; j < 16; ++j) a += hp[pD*16 + j]*wD2[j];
      a += __shfl_xor(a, 1); a += __shfl_xor(a, 2);
      if (pD == 0) out[2097152 + (size_t)(tok0 + tk)*32 + oD] = a;
    }
    __syncthreads();
    float v = ob[(t & 15)*16 + (t >> 4)];
    if ((t & 15) == 0) v += csl[t >> 4];
    out[(size_t)(tok0 + tk)*256 + t] = v;
    __syncthreads();
  }
}

// ---------------------------------------------------------------------------
extern "C" void kernel_launch(void* const* d_in, const int* in_sizes, int n_in,
                              void* d_out, int out_size, void* d_ws, size_t ws_size,
                              hipStream_t stream) {
  const float* mv_kv    = (const float*)d_in[0];
  const float* mv_q     = (const float*)d_in[1];
  const float* s_kv     = (const float*)d_in[2];
  const float* s_q      = (const float*)d_in[3];
  const float* w_mv_q   = (const float*)d_in[4];
  const float* w_s2mv_q = (const float*)d_in[5];
  const float* w_mv2s_q = (const float*)d_in[6];
  const float* w_s_q    = (const float*)d_in[7];
  const float* w_mv_kv   = (const float*)d_in[8];
  const float* w_s2mv_kv = (const float*)d_in[9];
  const float* w_mv2s_kv = (const float*)d_in[10];
  const float* w_s_kv    = (const float*)d_in[11];
  const float* w_mv_o   = (const float*)d_in[12];
  const float* w_s2mv_o = (const float*)d_in[13];
  const float* w_mv2s_o = (const float*)d_in[14];
  const float* w_s_o    = (const float*)d_in[15];
  const float* hscale   = (const float*)d_in[16];

  u16* qf = (u16*)d_ws;
  u16* kf = qf + 10485760;
  u16* vf = kf + 10485760;
  u16* ho = vf + 10485760;   // bf16 (b,h,n,144) = 9,437,184 u16

  k_proj_q <<<1024, 256, 0, stream>>>(mv_q,  s_q,  w_mv_q,  w_s2mv_q,  w_mv2s_q,  w_s_q,  qf);
  k_proj_kv<<<1024, 512, 0, stream>>>(mv_kv, s_kv, w_mv_kv, w_s2mv_kv, w_mv2s_kv, w_s_kv, kf, vf);
  k_attn   <<< 512, 256, 0, stream>>>(qf, kf, vf, hscale, ho);
  k_out    <<<1024, 256, 0, stream>>>(ho, w_mv_o, w_s2mv_o, w_mv2s_o, w_s_o, (float*)d_out);
}

// Round 24
// 222.754 us; speedup vs baseline: 1.2237x; 1.2237x over previous
//
#include <hip/hip_runtime.h>
#include <math.h>

// B=4, N=2048, H=8, CM=8, CS=16 ; head dim 144 padded to 160 (5 chunks of 32)
// qf/kf/vf: bf16 (b,h,n,160); ho: bf16 (b,h,n,144) head-contiguous
// Softmax in exp2 domain (QSCALE = (1/12)*log2(e) folded into q).
// V[d=144] = 1.0 so PV's dblk-9 accumulates the softmax denominator l.

typedef float f32x4 __attribute__((ext_vector_type(4)));
typedef __bf16 bf16x8 __attribute__((ext_vector_type(8)));
typedef unsigned short u16;
typedef unsigned int u32;

#define QSCALE 0.120224586740747f   // (1/12) * log2(e)
#define DEFER_THR 11.541560f        // 8 * log2(e)

__device__ __forceinline__ u32 pack2(float a, float b) {
  u32 ua = __builtin_bit_cast(u32, a);
  u32 ub = __builtin_bit_cast(u32, b);
  ua = (ua + 0x7fffu + ((ua >> 16) & 1u)) >> 16;
  ub = (ub + 0x7fffu + ((ub >> 16) & 1u)) >> 16;
  return ua | (ub << 16);
}
__device__ __forceinline__ u16 bf16of(float a) { return (u16)(pack2(a, 0.f) & 0xffffu); }

__device__ __forceinline__ u32 cvtpk(float lo, float hi) {
  u32 r;
  asm("v_cvt_pk_bf16_f32 %0, %1, %2" : "=v"(r) : "v"(lo), "v"(hi));
  return r;
}
__device__ __forceinline__ float lo16f(u32 w) { return __builtin_bit_cast(float, w << 16); }
__device__ __forceinline__ float hi16f(u32 w) { return __builtin_bit_cast(float, w & 0xffff0000u); }

__device__ __forceinline__ f32x4 mfma_bf16(uint4 a, uint4 b, f32x4 c) {
  return __builtin_amdgcn_mfma_f32_16x16x32_bf16(
      __builtin_bit_cast(bf16x8, a), __builtin_bit_cast(bf16x8, b), c, 0, 0, 0);
}

__device__ __forceinline__ uint2 tr16(u32 addr) {
  uint2 r;
  asm volatile("ds_read_b64_tr_b16 %0, %1" : "=v"(r) : "v"(addr));
  return r;
}

__device__ __forceinline__ void glds16(const void* g, void* l) {
  __builtin_amdgcn_global_load_lds((const __attribute__((address_space(1))) void*)g,
                                   (__attribute__((address_space(3))) void*)l, 16, 0, 0);
}

// ---------------------------------------------------------------------------
// Q projection (R20). 256 threads, 8 tokens/block. Direct global token reads
// (wave-uniform -> scalarized). Output staged in qs for coalesced stores.
// ---------------------------------------------------------------------------
__global__ __launch_bounds__(256) void k_proj_q(
    const float* __restrict__ mv, const float* __restrict__ sc,
    const float* __restrict__ w_mv, const float* __restrict__ w_s2mv,
    const float* __restrict__ w_mv2s, const float* __restrict__ w_s,
    u16* __restrict__ qf)
{
  __shared__ u16 qs[8*8*168];
  const int t = threadIdx.x;
  const int tok0 = blockIdx.x * 8;
  const int b0 = tok0 >> 11, n0 = tok0 & 2047;

  if (t < 128) {
    const int o = t & 63, h2 = t >> 6;
    float wreg[3][16];
    #pragma unroll
    for (int j = 0; j < 3; ++j)
      #pragma unroll
      for (int i = 0; i < 16; ++i)
        wreg[j][i] = w_mv[(((h2*2 + j)*64) + o)*16 + i];
    float ws2[32];
    if (h2 == 0)
      #pragma unroll
      for (int j = 0; j < 32; ++j) ws2[j] = w_s2mv[o*32 + j];
    const int c = o >> 3, hh = o & 7;
    for (int tk = 0; tk < 8; ++tk) {
      const float* L  = &mv[(size_t)(tok0+tk)*256];
      const float* Ls = &sc[(size_t)(tok0+tk)*32];
      float acc[8] = {0,0,0,0,0,0,0,0};
      if (h2 == 0) {
        #pragma unroll
        for (int i = 0; i < 16; ++i) {
          const float w0 = wreg[0][i], w1 = wreg[1][i], w2 = wreg[2][i];
          const float4 A = *(const float4*)&L[i*16];
          const float4 Bv = *(const float4*)&L[i*16 + 4];
          acc[0] += A.x*w0;  acc[1] += A.y*w1;  acc[2] += A.z*w1;  acc[3] += A.w*w1;
          acc[4] += Bv.x*w1; acc[5] += Bv.y*w2; acc[6] += Bv.z*w2; acc[7] += Bv.w*w2;
        }
        float a0 = 0.f;
        #pragma unroll
        for (int j4 = 0; j4 < 8; ++j4) {
          const float4 s4 = *(const float4*)&Ls[j4*4];
          a0 += s4.x*ws2[j4*4] + s4.y*ws2[j4*4+1] + s4.z*ws2[j4*4+2] + s4.w*ws2[j4*4+3];
        }
        acc[0] += a0;
        acc[0] *= QSCALE; acc[1] *= QSCALE;
        #pragma unroll
        for (int xx = 2; xx < 8; ++xx) acc[xx] *= -QSCALE;
      } else {
        #pragma unroll
        for (int i = 0; i < 16; ++i) {
          const float w0 = wreg[0][i], w1 = wreg[1][i], w2 = wreg[2][i];
          const float4 A = *(const float4*)&L[i*16 + 8];
          const float4 Bv = *(const float4*)&L[i*16 + 12];
          acc[0] += A.x*w0;  acc[1] += A.y*w0;  acc[2] += A.z*w0;  acc[3] += A.w*w1;
          acc[4] += Bv.x*w1; acc[5] += Bv.y*w1; acc[6] += Bv.z*w1; acc[7] += Bv.w*w2;
        }
        #pragma unroll
        for (int xx = 0; xx < 6; ++xx) acc[xx] *= QSCALE;
        acc[6] *= -QSCALE; acc[7] *= -QSCALE;
      }
      uint4 u; u.x = pack2(acc[0],acc[1]); u.y = pack2(acc[2],acc[3]);
      u.z = pack2(acc[4],acc[5]); u.w = pack2(acc[6],acc[7]);
      *(uint4*)&qs[(tk*8 + hh)*168 + c*16 + h2*8] = u;
    }
  } else {
    const int o2 = t - 128;
    float wsv[32], wm2[16];
    #pragma unroll
    for (int j = 0; j < 32; ++j) wsv[j] = w_s[o2*32 + j];
    #pragma unroll
    for (int i = 0; i < 16; ++i) wm2[i] = w_mv2s[o2*16 + i];
    const int cs = o2 >> 3, hh = o2 & 7;
    for (int tk = 0; tk < 8; ++tk) {
      const float* L  = &mv[(size_t)(tok0+tk)*256];
      const float* Ls = &sc[(size_t)(tok0+tk)*32];
      float a = 0.f;
      #pragma unroll
      for (int j4 = 0; j4 < 8; ++j4) {
        const float4 s4 = *(const float4*)&Ls[j4*4];
        a += s4.x*wsv[j4*4] + s4.y*wsv[j4*4+1] + s4.z*wsv[j4*4+2] + s4.w*wsv[j4*4+3];
      }
      #pragma unroll
      for (int i = 0; i < 16; ++i) a += L[i*16]*wm2[i];
      qs[(tk*8 + hh)*168 + 128 + cs] = bf16of(a * QSCALE);
    }
  }
  __syncthreads();
  for (int idx = t; idx < 8*8*20; idx += 256) {
    const int hh = idx / 160, rem = idx - hh*160;
    const int tk = rem / 20, u = rem - tk*20;
    uint4 v = (u < 18) ? *(const uint4*)&qs[(tk*8 + hh)*168 + u*8] : uint4{0,0,0,0};
    *(uint4*)(qf + ((size_t)(b0*8 + hh)*2048 + n0 + tk)*160 + u*8) = v;
  }
}

// ---------------------------------------------------------------------------
// KV projection (R20). 512 threads, 8 tokens/block, direct global reads.
// V pad gets bf16(1.0) at d=144.
// ---------------------------------------------------------------------------
__global__ __launch_bounds__(512) void k_proj_kv(
    const float* __restrict__ mv, const float* __restrict__ sc,
    const float* __restrict__ w_mv, const float* __restrict__ w_s2mv,
    const float* __restrict__ w_mv2s, const float* __restrict__ w_s,
    u16* __restrict__ kf, u16* __restrict__ vf)
{
  __shared__ u16 kvs[2*8*8*168];   // [isv][tk][hh][168]
  const int t = threadIdx.x;
  const int tok0 = blockIdx.x * 8;
  const int b0 = tok0 >> 11, n0 = tok0 & 2047;

  if (t < 256) {
    const int o = t & 127, h2 = t >> 7;
    float wreg[3][16];
    #pragma unroll
    for (int j = 0; j < 3; ++j)
      #pragma unroll
      for (int i = 0; i < 16; ++i)
        wreg[j][i] = w_mv[(((h2*2 + j)*128) + o)*16 + i];
    float ws2[32];
    if (h2 == 0)
      #pragma unroll
      for (int j = 0; j < 32; ++j) ws2[j] = w_s2mv[o*32 + j];
    const int isv = o >> 6, oo = o & 63;
    const int c = oo >> 3, hh = oo & 7;
    u16* stg = &kvs[isv*8*8*168];
    for (int tk = 0; tk < 8; ++tk) {
      const float* L  = &mv[(size_t)(tok0+tk)*256];
      const float* Ls = &sc[(size_t)(tok0+tk)*32];
      float acc[8] = {0,0,0,0,0,0,0,0};
      if (h2 == 0) {
        #pragma unroll
        for (int i = 0; i < 16; ++i) {
          const float w0 = wreg[0][i], w1 = wreg[1][i], w2 = wreg[2][i];
          const float4 A = *(const float4*)&L[i*16];
          const float4 Bv = *(const float4*)&L[i*16 + 4];
          acc[0] += A.x*w0;  acc[1] += A.y*w1;  acc[2] += A.z*w1;  acc[3] += A.w*w1;
          acc[4] += Bv.x*w1; acc[5] += Bv.y*w2; acc[6] += Bv.z*w2; acc[7] += Bv.w*w2;
        }
        float a0 = 0.f;
        #pragma unroll
        for (int j4 = 0; j4 < 8; ++j4) {
          const float4 s4 = *(const float4*)&Ls[j4*4];
          a0 += s4.x*ws2[j4*4] + s4.y*ws2[j4*4+1] + s4.z*ws2[j4*4+2] + s4.w*ws2[j4*4+3];
        }
        acc[0] += a0;
      } else {
        #pragma unroll
        for (int i = 0; i < 16; ++i) {
          const float w0 = wreg[0][i], w1 = wreg[1][i], w2 = wreg[2][i];
          const float4 A = *(const float4*)&L[i*16 + 8];
          const float4 Bv = *(const float4*)&L[i*16 + 12];
          acc[0] += A.x*w0;  acc[1] += A.y*w0;  acc[2] += A.z*w0;  acc[3] += A.w*w1;
          acc[4] += Bv.x*w1; acc[5] += Bv.y*w1; acc[6] += Bv.z*w1; acc[7] += Bv.w*w2;
        }
      }
      uint4 u; u.x = pack2(acc[0],acc[1]); u.y = pack2(acc[2],acc[3]);
      u.z = pack2(acc[4],acc[5]); u.w = pack2(acc[6],acc[7]);
      *(uint4*)&stg[(tk*8 + hh)*168 + c*16 + h2*8] = u;
    }
  } else {
    const int o2 = t - 256;
    float wsv[32], wm2[16];
    #pragma unroll
    for (int j = 0; j < 32; ++j) wsv[j] = w_s[o2*32 + j];
    #pragma unroll
    for (int i = 0; i < 16; ++i) wm2[i] = w_mv2s[o2*16 + i];
    const int isv = o2 >> 7, oo2 = o2 & 127;
    const int cs = oo2 >> 3, hh = oo2 & 7;
    u16* stg = &kvs[isv*8*8*168];
    for (int tk = 0; tk < 8; ++tk) {
      const float* L  = &mv[(size_t)(tok0+tk)*256];
      const float* Ls = &sc[(size_t)(tok0+tk)*32];
      float a = 0.f;
      #pragma unroll
      for (int j4 = 0; j4 < 8; ++j4) {
        const float4 s4 = *(const float4*)&Ls[j4*4];
        a += s4.x*wsv[j4*4] + s4.y*wsv[j4*4+1] + s4.z*wsv[j4*4+2] + s4.w*wsv[j4*4+3];
      }
      #pragma unroll
      for (int i = 0; i < 16; ++i) a += L[i*16]*wm2[i];
      stg[(tk*8 + hh)*168 + 128 + cs] = bf16of(a);
    }
  }
  __syncthreads();
  for (int idx = t; idx < 2560; idx += 512) {
    const int isv = idx / 1280;
    const int r = idx - isv*1280;
    const int hh = r / 160, rem = r - hh*160;
    const int tk = rem / 20, u = rem - tk*20;
    uint4 v;
    if (u < 18)               v = *(const uint4*)&kvs[isv*8*8*168 + (tk*8 + hh)*168 + u*8];
    else if (u == 18 && isv)  v = uint4{0x3F80u, 0, 0, 0};   // V[d=144] = 1.0
    else                      v = uint4{0, 0, 0, 0};
    u16* base = isv ? vf : kf;
    *(uint4*)(base + ((size_t)(b0*8 + hh)*2048 + n0 + tk)*160 + u*8) = v;
  }
}

// ---------------------------------------------------------------------------
// Flash attention (R19/R22): KVBLK=64, bf16 MFMA, exp2 softmax, l-in-MFMA,
// bf16 ho epilogue. K+V double-buffered via global_load_lds.
// LDS: 2 x 40960 = 81920 B -> 2 blk/CU.
// ---------------------------------------------------------------------------
__global__ __launch_bounds__(256, 2) void k_attn(
    const u16* __restrict__ qf, const u16* __restrict__ kf,
    const u16* __restrict__ vf, const float* __restrict__ hsc,
    u16* __restrict__ ho)
{
  __shared__ __align__(16) char smem[81920];

  const int orig = blockIdx.x;
  const int bid = (orig & 7) * 64 + (orig >> 3);   // XCD-contiguous (512%8==0)
  const int qt = bid & 15;
  const int bh = bid >> 4;
  const int h  = bh & 7;
  const int t  = threadIdx.x;
  const int w  = t >> 6;
  const int lane = t & 63;
  const int qi = lane & 15;
  const int hi = lane >> 4;

  const char* kgB = (const char*)(kf + (size_t)bh * 2048 * 160);
  const char* vgB = (const char*)(vf + (size_t)bh * 2048 * 160);
  const u16* qg = qf + ((size_t)bh * 2048 + qt*128 + w*32) * 160;
  const float hsv = hsc[h];

  uint4 qfr0[5], qfr1[5];
  #pragma unroll
  for (int dc = 0; dc < 5; ++dc) {
    qfr0[dc] = *(const uint4*)(qg + (size_t)qi*160 + dc*32 + hi*8);
    qfr1[dc] = *(const uint4*)(qg + (size_t)(16 + qi)*160 + dc*32 + hi*8);
  }

  f32x4 o0[10], o1[10];
  #pragma unroll
  for (int d = 0; d < 10; ++d) { o0[d] = f32x4{0,0,0,0}; o1[d] = f32x4{0,0,0,0}; }
  float m0 = -INFINITY, m1 = -INFINITY;

  int soff[10];
  if (w < 2) {
    #pragma unroll
    for (int j = 0; j < 10; ++j) soff[j] = w*10240 + j*1024 + lane*16;
  } else {
    #pragma unroll
    for (int j = 0; j < 10; ++j) {
      const int p = (w-2)*10240 + j*1024 + lane*16;
      const int kblk = p / 5120, r1 = p - kblk*5120;
      const int dblk = r1 >> 9, r2 = r1 & 511;
      const int krow = r2 >> 5, dhalf = (r2 >> 4) & 1;
      soff[j] = (kblk*16 + krow)*320 + dblk*32 + dhalf*16;
    }
  }

  #define STAGE(KT, BUF) do {                                              \
    char* base_ = smem + (BUF)*40960;                                      \
    if (w < 2) {                                                           \
      const char* src_ = kgB + (size_t)(KT)*20480;                         \
      _Pragma("unroll")                                                    \
      for (int j = 0; j < 10; ++j)                                         \
        glds16(src_ + soff[j], base_ + w*10240 + j*1024);                  \
    } else {                                                               \
      const char* src_ = vgB + (size_t)(KT)*20480;                         \
      char* vb_ = base_ + 20480 + (w-2)*10240;                             \
      _Pragma("unroll")                                                    \
      for (int j = 0; j < 10; ++j)                                         \
        glds16(src_ + soff[j], vb_ + j*1024);                              \
    }                                                                      \
  } while (0)

  STAGE(0, 0);
  __syncthreads();

  for (int kt = 0; kt < 32; ++kt) {
    const int buf = kt & 1;
    if (kt < 31) STAGE(kt+1, buf^1);

    const char* KsB = smem + buf*40960;
    const u32 VoffB = (u32)(buf*40960 + 20480);

    f32x4 st0[4], st1[4];
    __builtin_amdgcn_s_setprio(1);
    #pragma unroll
    for (int ks = 0; ks < 4; ++ks) {
      st0[ks] = f32x4{0,0,0,0};
      st1[ks] = f32x4{0,0,0,0};
      #pragma unroll
      for (int dc = 0; dc < 5; ++dc) {
        const uint4 kf4 = *(const uint4*)(KsB + (ks*16 + qi)*320 + dc*64 + hi*16);
        st0[ks] = mfma_bf16(kf4, qfr0[dc], st0[ks]);
        st1[ks] = mfma_bf16(kf4, qfr1[dc], st1[ks]);
      }
    }
    __builtin_amdgcn_s_setprio(0);

    float pm0 = st0[0][0], pm1 = st1[0][0];
    #pragma unroll
    for (int ks = 0; ks < 4; ++ks)
      #pragma unroll
      for (int r = 0; r < 4; ++r) {
        pm0 = fmaxf(pm0, st0[ks][r]);
        pm1 = fmaxf(pm1, st1[ks][r]);
      }
    pm0 = fmaxf(pm0, __shfl_xor(pm0, 16)); pm0 = fmaxf(pm0, __shfl_xor(pm0, 32));
    pm1 = fmaxf(pm1, __shfl_xor(pm1, 16)); pm1 = fmaxf(pm1, __shfl_xor(pm1, 32));
    if (!__all(fmaxf(pm0 - m0, pm1 - m1) <= DEFER_THR)) {
      const float mn0 = fmaxf(m0, pm0), mn1 = fmaxf(m1, pm1);
      const float rs0 = exp2f(m0 - mn0), rs1 = exp2f(m1 - mn1);
      m0 = mn0; m1 = mn1;
      float rr0[4], rr1[4];
      #pragma unroll
      for (int r = 0; r < 4; ++r) {
        rr0[r] = __shfl(rs0, hi*4 + r);
        rr1[r] = __shfl(rs1, hi*4 + r);
      }
      #pragma unroll
      for (int d = 0; d < 10; ++d)
        #pragma unroll
        for (int r = 0; r < 4; ++r) { o0[d][r] *= rr0[r]; o1[d][r] *= rr1[r]; }
    }
    #pragma unroll
    for (int ks = 0; ks < 4; ++ks)
      #pragma unroll
      for (int r = 0; r < 4; ++r) {
        st0[ks][r] = exp2f(st0[ks][r] - m0);
        st1[ks][r] = exp2f(st1[ks][r] - m1);
      }

    uint4 pb0a, pb0b, pb1a, pb1b;
    pb0a.x = cvtpk(st0[0][0], st0[0][1]); pb0a.y = cvtpk(st0[0][2], st0[0][3]);
    pb0a.z = cvtpk(st0[1][0], st0[1][1]); pb0a.w = cvtpk(st0[1][2], st0[1][3]);
    pb0b.x = cvtpk(st0[2][0], st0[2][1]); pb0b.y = cvtpk(st0[2][2], st0[2][3]);
    pb0b.z = cvtpk(st0[3][0], st0[3][1]); pb0b.w = cvtpk(st0[3][2], st0[3][3]);
    pb1a.x = cvtpk(st1[0][0], st1[0][1]); pb1a.y = cvtpk(st1[0][2], st1[0][3]);
    pb1a.z = cvtpk(st1[1][0], st1[1][1]); pb1a.w = cvtpk(st1[1][2], st1[1][3]);
    pb1b.x = cvtpk(st1[2][0], st1[2][1]); pb1b.y = cvtpk(st1[2][2], st1[2][3]);
    pb1b.z = cvtpk(st1[3][0], st1[3][1]); pb1b.w = cvtpk(st1[3][2], st1[3][3]);

    const u32 vtb = VoffB + (u32)(hi*128 + (qi>>2)*32 + (qi&3)*8);
    __builtin_amdgcn_s_setprio(1);
    #pragma unroll
    for (int ds = 0; ds < 10; ++ds) {
      const u32 a0 = vtb + ds*512;
      uint2 t0 = tr16(a0);
      uint2 t1 = tr16(a0 + 5120);
      uint2 t2 = tr16(a0 + 10240);
      uint2 t3 = tr16(a0 + 15360);
      asm volatile("s_waitcnt lgkmcnt(0)" ::: "memory");
      __builtin_amdgcn_sched_barrier(0);
      const uint4 vb01{t0.x, t0.y, t1.x, t1.y};
      const uint4 vb23{t2.x, t2.y, t3.x, t3.y};
      o0[ds] = mfma_bf16(pb0a, vb01, o0[ds]);
      o0[ds] = mfma_bf16(pb0b, vb23, o0[ds]);
      o1[ds] = mfma_bf16(pb1a, vb01, o1[ds]);
      o1[ds] = mfma_bf16(pb1b, vb23, o1[ds]);
    }
    __builtin_amdgcn_s_setprio(0);

    __syncthreads();
  }

  // ---- epilogue: bf16 ho stores ----
  float ir0[4], ir1[4];
  #pragma unroll
  for (int r = 0; r < 4; ++r) {
    ir0[r] = hsv / __shfl(o0[9][r], hi*16);
    ir1[r] = hsv / __shfl(o1[9][r], hi*16);
  }
  float (*Ol)[148] = reinterpret_cast<float(*)[148]>(smem);
  const size_t obase = ((size_t)bh*2048 + qt*128) * 144;
  #pragma unroll
  for (int f = 0; f < 2; ++f) {
    #pragma unroll
    for (int ds = 0; ds < 9; ++ds)
      #pragma unroll
      for (int r = 0; r < 4; ++r) {
        const int q = w*16 + hi*4 + r;
        const int loc = (ds < 8) ? (qi*8 + ds) : (128 + qi);
        Ol[q][loc] = (f ? o1[ds][r]*ir1[r] : o0[ds][r]*ir0[r]);
      }
    __syncthreads();
    for (int idx = t; idx < 64*18; idx += 256) {
      const int q = idx / 18, u = idx - q*18;
      const int grow = (q >> 4)*32 + f*16 + (q & 15);
      const float4 a = *(const float4*)&Ol[q][u*8];
      const float4 b = *(const float4*)&Ol[q][u*8 + 4];
      uint4 pk;
      pk.x = cvtpk(a.x, a.y); pk.y = cvtpk(a.z, a.w);
      pk.z = cvtpk(b.x, b.y); pk.w = cvtpk(b.z, b.w);
      *(uint4*)(ho + obase + (size_t)grow*144 + u*8) = pk;
    }
    __syncthreads();
  }
  #undef STAGE
}

// ---------------------------------------------------------------------------
// Output projection (R18/R20). 256 threads, 8 tokens/block, bf16 ho input.
// Gather-fill into LDS (coalesced), compute from LDS.
// ---------------------------------------------------------------------------
__global__ __launch_bounds__(256) void k_out(
    const u16* __restrict__ ho,
    const float* __restrict__ w_mv, const float* __restrict__ w_s2mv,
    const float* __restrict__ w_mv2s, const float* __restrict__ w_s,
    float* __restrict__ out)
{
  constexpr int kGx[16] = {0,1,1,1,1,2,2,2,2,2,2,3,3,3,3,4};
  __shared__ float lh[8*1152];
  __shared__ float ob[256];
  __shared__ float csl[16];
  const int t = threadIdx.x;
  const int tok0 = blockIdx.x * 8;
  const int b0 = tok0 >> 11, n0 = tok0 & 2047;

  const int x = t >> 4, oB = t & 15;
  float4 wB[16];
  #pragma unroll
  for (int q = 0; q < 16; ++q)
    wB[q] = *(const float4*)&w_mv[(kGx[x]*16 + oB)*64 + q*4];

  float wC[16];
  float wD1[32], wD2[16];
  int oC = 0, pC = 0, oD = 0, pD = 0;
  if (t < 128) {
    oC = t >> 3; pC = t & 7;
    #pragma unroll
    for (int j = 0; j < 16; ++j) wC[j] = w_s2mv[oC*128 + pC*16 + j];
  } else {
    const int tt = t - 128;
    oD = tt >> 2; pD = tt & 3;
    #pragma unroll
    for (int j = 0; j < 32; ++j) wD1[j] = w_s[oD*128 + pD*32 + j];
    #pragma unroll
    for (int j = 0; j < 16; ++j) wD2[j] = w_mv2s[oD*64 + pD*16 + j];
  }

  // gather-fill: 8 tk x 8 heads x 18 uint4 (8 bf16 each)
  for (int idx = t; idx < 1152; idx += 256) {
    const int tk = idx / 144, rem = idx - tk*144;
    const int hh = rem / 18, u8 = rem - hh*18;
    const uint4 v = *(const uint4*)&ho[(((size_t)(b0*8 + hh)*2048) + n0 + tk)*144 + u8*8];
    float* Lt = &lh[tk*1152];
    const int dst = (u8 < 16) ? (u8*64 + hh*8) : (1024 + hh*16 + (u8-16)*8);
    *(float4*)&Lt[dst]     = float4{lo16f(v.x), hi16f(v.x), lo16f(v.y), hi16f(v.y)};
    *(float4*)&Lt[dst + 4] = float4{lo16f(v.z), hi16f(v.z), lo16f(v.w), hi16f(v.w)};
  }
  __syncthreads();

  for (int tk = 0; tk < 8; ++tk) {
    const float* hp = &lh[tk*1152];
    float acc = 0.f;
    #pragma unroll
    for (int q = 0; q < 16; ++q) {
      const float4 hv = *(const float4*)&hp[x*64 + q*4];
      acc += hv.x*wB[q].x + hv.y*wB[q].y + hv.z*wB[q].z + hv.w*wB[q].w;
    }
    ob[t] = acc;
    if (t < 128) {
      float a = 0.f;
      #pragma unroll
      for (int j = 0; j < 16; ++j) a += hp[1024 + pC*16 + j]*wC[j];
      a += __shfl_xor(a, 1); a += __shfl_xor(a, 2); a += __shfl_xor(a, 4);
      if (pC == 0) csl[oC] = a;
    } else {
      float a = 0.f;
      #pragma unroll
      for (int j = 0; j < 32; ++j) a += hp[1024 + pD*32 + j]*wD1[j];
      #pragma unroll
      for (int j = 0; j < 16; ++j) a += hp[pD*16 + j]*wD2[j];
      a += __shfl_xor(a, 1); a += __shfl_xor(a, 2);
      if (pD == 0) out[2097152 + (size_t)(tok0 + tk)*32 + oD] = a;
    }
    __syncthreads();
    float v = ob[(t & 15)*16 + (t >> 4)];
    if ((t & 15) == 0) v += csl[t >> 4];
    out[(size_t)(tok0 + tk)*256 + t] = v;
    __syncthreads();
  }
}

// ---------------------------------------------------------------------------
extern "C" void kernel_launch(void* const* d_in, const int* in_sizes, int n_in,
                              void* d_out, int out_size, void* d_ws, size_t ws_size,
                              hipStream_t stream) {
  const float* mv_kv    = (const float*)d_in[0];
  const float* mv_q     = (const float*)d_in[1];
  const float* s_kv     = (const float*)d_in[2];
  const float* s_q      = (const float*)d_in[3];
  const float* w_mv_q   = (const float*)d_in[4];
  const float* w_s2mv_q = (const float*)d_in[5];
  const float* w_mv2s_q = (const float*)d_in[6];
  const float* w_s_q    = (const float*)d_in[7];
  const float* w_mv_kv   = (const float*)d_in[8];
  const float* w_s2mv_kv = (const float*)d_in[9];
  const float* w_mv2s_kv = (const float*)d_in[10];
  const float* w_s_kv    = (const float*)d_in[11];
  const float* w_mv_o   = (const float*)d_in[12];
  const float* w_s2mv_o = (const float*)d_in[13];
  const float* w_mv2s_o = (const float*)d_in[14];
  const float* w_s_o    = (const float*)d_in[15];
  const float* hscale   = (const float*)d_in[16];

  u16* qf = (u16*)d_ws;
  u16* kf = qf + 10485760;
  u16* vf = kf + 10485760;
  u16* ho = vf + 10485760;   // bf16 (b,h,n,144) = 9,437,184 u16

  k_proj_q <<<1024, 256, 0, stream>>>(mv_q,  s_q,  w_mv_q,  w_s2mv_q,  w_mv2s_q,  w_s_q,  qf);
  k_proj_kv<<<1024, 512, 0, stream>>>(mv_kv, s_kv, w_mv_kv, w_s2mv_kv, w_mv2s_kv, w_s_kv, kf, vf);
  k_attn   <<< 512, 256, 0, stream>>>(qf, kf, vf, hscale, ho);
  k_out    <<<1024, 256, 0, stream>>>(ho, w_mv_o, w_s2mv_o, w_mv2s_o, w_s_o, (float*)d_out);
}